// Round 5
// baseline (726.189 us; speedup 1.0000x reference)
//
#include <hip/hip_runtime.h>

#define BB 512
#define SS 256
#define HH 128
#define NC 10

typedef float v2f __attribute__((ext_vector_type(2)));

// acc + (give from lane selected by DPP ctrl)
template<int CTRL>
__device__ __forceinline__ float dppadd(float acc, float give) {
    int t = __builtin_amdgcn_update_dpp(0, __float_as_int(give), CTRL, 0xF, 0xF, true);
    return acc + __int_as_float(t);
}

// cndmask-free reduce-scatter over the 16-lane group (verified).
// Input v[8] in permuted slot order (slot i = column 8j + (i^(r&7))).
// Returns full sum for column 8j + (r&7); copies at lanes r and r^8.
__device__ __forceinline__ float red_scatter(const float v[8], int r) {
    float s0 = dppadd<0xB1>(v[0], v[1]);    // xor1
    float s2 = dppadd<0xB1>(v[2], v[3]);
    float s4 = dppadd<0xB1>(v[4], v[5]);
    float s6 = dppadd<0xB1>(v[6], v[7]);
    s0 = dppadd<0x4E>(s0, s2);              // xor2
    s4 = dppadd<0x4E>(s4, s6);
    {   // xor4 via row_ror 4 / 12
        int t1 = __builtin_amdgcn_update_dpp(0, __float_as_int(s4), 0x124, 0xF, 0xF, true);
        int t2 = __builtin_amdgcn_update_dpp(0, __float_as_int(s4), 0x12C, 0xF, 0xF, true);
        s0 += __int_as_float((r & 4) ? t2 : t1);
    }
    s0 = dppadd<0x128>(s0, s0);             // xor8 (row_ror:8)
    return s0;
}

// Barrier without the compiler's vmcnt(0) drain (LDS-visibility only).
__device__ __forceinline__ void barrier_nodrain() {
    asm volatile("s_waitcnt lgkmcnt(0)\n\ts_barrier" ::: "memory");
}

// =====================================================================
// proj_k: out[m][j] = sum_d A[m][d] * W[j][d]   (NO bias — scans add it)
// Layer 0 input projection only (K=28).  (Proven kernel, unchanged.)
// =====================================================================
template<int K>
__global__ __launch_bounds__(256, 1)
void proj_k(const float* __restrict__ A, const float* __restrict__ W,
            float* __restrict__ out)
{
    constexpr int AS = ((K + 31) / 32) * 32 + 4;
    constexpr int KQ = K / 4;
    constexpr int KCW = (K < 32) ? K : 32;
    constexpr int WQ = KCW / 4;
    const int tid = threadIdx.x;
    const int tx = tid & 15;
    const int ty = tid >> 4;
    const size_t m0 = (size_t)blockIdx.x * 64;

    __shared__ float Arm[64 * AS];
    __shared__ float Wst[128 * 36];

    for (int idx = tid; idx < 64 * KQ; idx += 256) {
        const int row = idx / KQ, kq = idx % KQ;
        const float4 v = *(const float4*)(A + (m0 + row) * K + 4 * kq);
        *(float4*)(&Arm[row * AS + 4 * kq]) = v;
    }

    float acc[4][8];
    #pragma unroll
    for (int c = 0; c < 8; ++c)
        #pragma unroll
        for (int r = 0; r < 4; ++r) acc[r][c] = 0.f;

    #pragma unroll 1
    for (int kc = 0; kc < K; kc += KCW) {
        __syncthreads();
        for (int idx = tid; idx < 128 * WQ; idx += 256) {
            const int col = idx / WQ, q = idx % WQ;
            const float4 v = *(const float4*)(W + (size_t)col * K + kc + 4 * q);
            *(float4*)(&Wst[col * 36 + 4 * q]) = v;
        }
        __syncthreads();
        #pragma unroll 2
        for (int q = 0; q < WQ; ++q) {
            float4 av[4];
            #pragma unroll
            for (int r = 0; r < 4; ++r)
                av[r] = *(const float4*)(&Arm[(ty + 16 * r) * AS + kc + 4 * q]);
            #pragma unroll
            for (int c = 0; c < 8; ++c) {
                const float4 wv = *(const float4*)(&Wst[(tx + 16 * c) * 36 + 4 * q]);
                #pragma unroll
                for (int r = 0; r < 4; ++r)
                    acc[r][c] += av[r].x * wv.x + av[r].y * wv.y
                               + av[r].z * wv.z + av[r].w * wv.w;
            }
        }
    }

    #pragma unroll
    for (int r = 0; r < 4; ++r)
        #pragma unroll
        for (int c = 0; c < 8; ++c)
            out[(m0 + ty + 16 * r) * HH + tx + 16 * c] = acc[r][c];
}

// =====================================================================
// scan_split2 (layers 0..2): grid 256; each block runs TWO batches
// (2*blk, 2*blk+1). 512 threads = rec-256 + proj-256; each thread
// processes BOTH batches with one shared weight fragment (64 floats).
// Rationale (R0-R4 counters): per-step wall ~1740cyc is invariant to
// occupancy (convoy effect between co-resident blocks); busy is 2x the
// hand count (VGPR_Count=52 => weights were AGPR'd, accvgpr_read per
// MAC operand). Fix: waves_per_eu(2,2) -> 256-reg cap, weights stay in
// arch VGPRs; 2 independent batch chains per thread fill the
// ds_read/DPP/tanh dependency stalls at instruction level.
// In-place safety per batch unchanged: row X stage-read at X-8,
// proj-written at X+1.
// =====================================================================
__global__ __attribute__((amdgpu_flat_work_group_size(512, 512),
                          amdgpu_waves_per_eu(2, 2)))
void scan_split2(float* __restrict__ buf,
                 const float* __restrict__ w_hh, const float* __restrict__ w_ih_next,
                 const float* __restrict__ b_ih_l, const float* __restrict__ b_hh_l)
{
    const int blk  = blockIdx.x;
    const int tid  = threadIdx.x;
    const int wg   = tid >> 8;       // 0 = recurrence, 1 = projection+staging
    const int t256 = tid & 255;
    const int j   = t256 >> 4;       // col group: cols 8j..8j+7
    const int r   = t256 & 15;       // k-chunk [8r, 8r+8)
    const int g7  = r & 7;
    const int cc  = 8 * j + g7;      // column this lane finalizes
    const int wsw = 12 * j + g7;     // its swizzled LDS word

    float* const rowA = buf + (size_t)(2 * blk) * SS * HH;
    float* const rowB = rowA + (size_t)SS * HH;
    const float bias = b_ih_l[cc] + b_hh_l[cc];     // used by wg0 only

    // permuted weights: slot i = column 8j + (i^g7), k-pair p
    const float* wsrc = wg ? w_ih_next : w_hh;
    v2f w[8][4];
    #pragma unroll
    for (int i = 0; i < 8; ++i) {
        const v2f* p = (const v2f*)(wsrc + (size_t)(8 * j + (i ^ g7)) * HH + 8 * r);
        w[i][0] = p[0]; w[i][1] = p[1]; w[i][2] = p[2]; w[i][3] = p[3];
    }

    __shared__ float hswA[2][192];       // h[k] at word 12*(k>>3)+(k&7)
    __shared__ float hswB[2][192];
    __shared__ float xwlA[2][8][HH];     // 8-step xw double buffers
    __shared__ float xwlB[2][8][HH];

    if (tid < 192) { hswA[0][tid] = 0.f; hswB[0][tid] = 0.f; }
    const int t   = t256 >> 5;           // staging: step-in-chunk
    const int pos = (t256 & 31) * 4;     // staging: column (float4)
    if (wg == 1) {                       // stage xw for steps 0..7, both batches
        const float4 vA = *(const float4*)(rowA + (size_t)t * HH + pos);
        const float4 vB = *(const float4*)(rowB + (size_t)t * HH + pos);
        *(float4*)(&xwlA[0][t][pos]) = vA;
        *(float4*)(&xwlB[0][t][pos]) = vB;
    }
    __syncthreads();

    int cur = 0;
    for (int s = 0; s < SS; ++s) {
        const int ph = s & 7, cb = (s >> 3) & 1;
        const bool do_stage = (wg == 1) && (ph == 0) && (s + 8 < SS);
        float4 stgA, stgB;
        if (do_stage) {
            stgA = *(const float4*)(rowA + (size_t)(s + 8 + t) * HH + pos);
            stgB = *(const float4*)(rowB + (size_t)(s + 8 + t) * HH + pos);
        }
        float myxwA = 0.f, myxwB = 0.f;
        if (wg == 0) {
            myxwA = xwlA[cb][ph][cc] + bias;
            myxwB = xwlB[cb][ph][cc] + bias;
        }

        // h_{s-1} fragments, both batches
        const v2f* hbA = (const v2f*)&hswA[cur][12 * r];
        const v2f* hbB = (const v2f*)&hswB[cur][12 * r];
        const v2f hA0 = hbA[0], hA1 = hbA[1], hA2 = hbA[2], hA3 = hbA[3];
        const v2f hB0 = hbB[0], hB1 = hbB[1], hB2 = hbB[2], hB3 = hbB[3];

        // two independent MAC+reduce chains (ILP fills serial stalls)
        float vA[8], vB[8];
        #pragma unroll
        for (int i = 0; i < 8; ++i) {
            v2f a = hA0 * w[i][0];
            a += hA1 * w[i][1];
            a += hA2 * w[i][2];
            a += hA3 * w[i][3];
            vA[i] = a.x + a.y;
            v2f bq = hB0 * w[i][0];
            bq += hB1 * w[i][1];
            bq += hB2 * w[i][2];
            bq += hB3 * w[i][3];
            vB[i] = bq.x + bq.y;
        }
        const float resA = red_scatter(vA, r);
        const float resB = red_scatter(vB, r);

        if (wg == 0) {
            const float zA = resA + myxwA;
            const float zB = resB + myxwB;
            const float eA = __expf(2.f * zA);
            const float eB = __expf(2.f * zB);
            const float hnA = 1.f - 2.f * __builtin_amdgcn_rcpf(1.f + eA);  // tanh
            const float hnB = 1.f - 2.f * __builtin_amdgcn_rcpf(1.f + eB);
            if (r < 8) {
                hswA[cur ^ 1][wsw] = hnA;
                hswB[cur ^ 1][wsw] = hnB;
            }
        } else {
            if (s > 0 && r < 8) {
                rowA[(size_t)(s - 1) * HH + cc] = resA;
                rowB[(size_t)(s - 1) * HH + cc] = resB;
            }
            if (do_stage) {
                *(float4*)(&xwlA[cb ^ 1][t][pos]) = stgA;
                *(float4*)(&xwlB[cb ^ 1][t][pos]) = stgB;
            }
        }
        barrier_nodrain();
        cur ^= 1;
    }

    // epilogue: project h_{SS-1} for both batches
    if (wg == 1) {
        const v2f* hbA = (const v2f*)&hswA[cur][12 * r];
        const v2f* hbB = (const v2f*)&hswB[cur][12 * r];
        const v2f hA0 = hbA[0], hA1 = hbA[1], hA2 = hbA[2], hA3 = hbA[3];
        const v2f hB0 = hbB[0], hB1 = hbB[1], hB2 = hbB[2], hB3 = hbB[3];
        float uA[8], uB[8];
        #pragma unroll
        for (int i = 0; i < 8; ++i) {
            v2f a = hA0 * w[i][0];
            a += hA1 * w[i][1];
            a += hA2 * w[i][2];
            a += hA3 * w[i][3];
            uA[i] = a.x + a.y;
            v2f bq = hB0 * w[i][0];
            bq += hB1 * w[i][1];
            bq += hB2 * w[i][2];
            bq += hB3 * w[i][3];
            uB[i] = bq.x + bq.y;
        }
        const float xwA = red_scatter(uA, r);
        const float xwB = red_scatter(uB, r);
        if (r < 8) {
            rowA[(size_t)(SS - 1) * HH + cc] = xwA;
            rowB[(size_t)(SS - 1) * HH + cc] = xwB;
        }
    }
}

// =====================================================================
// scan_last2 (layer 3): grid 256, 256 threads, recurrence only, two
// batches per thread. Threads stage their own xw (all 256 participate,
// both batches). Writes final h for both batches.
// =====================================================================
__global__ __attribute__((amdgpu_flat_work_group_size(256, 256),
                          amdgpu_waves_per_eu(2, 2)))
void scan_last2(const float* __restrict__ buf, float* __restrict__ hfin,
                const float* __restrict__ w_hh,
                const float* __restrict__ b_ih_l, const float* __restrict__ b_hh_l)
{
    const int blk = blockIdx.x;
    const int tid = threadIdx.x;
    const int j   = tid >> 4;
    const int r   = tid & 15;
    const int g7  = r & 7;
    const int cc  = 8 * j + g7;
    const int wsw = 12 * j + g7;

    const float* const rowA = buf + (size_t)(2 * blk) * SS * HH;
    const float* const rowB = rowA + (size_t)SS * HH;
    const float bias = b_ih_l[cc] + b_hh_l[cc];

    v2f w[8][4];
    #pragma unroll
    for (int i = 0; i < 8; ++i) {
        const v2f* p = (const v2f*)(w_hh + (size_t)(8 * j + (i ^ g7)) * HH + 8 * r);
        w[i][0] = p[0]; w[i][1] = p[1]; w[i][2] = p[2]; w[i][3] = p[3];
    }

    __shared__ float hswA[2][192];
    __shared__ float hswB[2][192];
    __shared__ float xwlA[2][8][HH];
    __shared__ float xwlB[2][8][HH];

    if (tid < 192) { hswA[0][tid] = 0.f; hswB[0][tid] = 0.f; }
    const int t   = tid >> 5;
    const int pos = (tid & 31) * 4;
    {
        const float4 vA = *(const float4*)(rowA + (size_t)t * HH + pos);
        const float4 vB = *(const float4*)(rowB + (size_t)t * HH + pos);
        *(float4*)(&xwlA[0][t][pos]) = vA;
        *(float4*)(&xwlB[0][t][pos]) = vB;
    }
    __syncthreads();

    int cur = 0;
    for (int s = 0; s < SS; ++s) {
        const int ph = s & 7, cb = (s >> 3) & 1;
        const bool do_stage = (ph == 0) && (s + 8 < SS);
        float4 stgA, stgB;
        if (do_stage) {
            stgA = *(const float4*)(rowA + (size_t)(s + 8 + t) * HH + pos);
            stgB = *(const float4*)(rowB + (size_t)(s + 8 + t) * HH + pos);
        }
        const float myxwA = xwlA[cb][ph][cc] + bias;
        const float myxwB = xwlB[cb][ph][cc] + bias;

        const v2f* hbA = (const v2f*)&hswA[cur][12 * r];
        const v2f* hbB = (const v2f*)&hswB[cur][12 * r];
        const v2f hA0 = hbA[0], hA1 = hbA[1], hA2 = hbA[2], hA3 = hbA[3];
        const v2f hB0 = hbB[0], hB1 = hbB[1], hB2 = hbB[2], hB3 = hbB[3];

        float vA[8], vB[8];
        #pragma unroll
        for (int i = 0; i < 8; ++i) {
            v2f a = hA0 * w[i][0];
            a += hA1 * w[i][1];
            a += hA2 * w[i][2];
            a += hA3 * w[i][3];
            vA[i] = a.x + a.y;
            v2f bq = hB0 * w[i][0];
            bq += hB1 * w[i][1];
            bq += hB2 * w[i][2];
            bq += hB3 * w[i][3];
            vB[i] = bq.x + bq.y;
        }
        const float zA = red_scatter(vA, r) + myxwA;
        const float zB = red_scatter(vB, r) + myxwB;
        const float eA = __expf(2.f * zA);
        const float eB = __expf(2.f * zB);
        const float hnA = 1.f - 2.f * __builtin_amdgcn_rcpf(1.f + eA);  // tanh
        const float hnB = 1.f - 2.f * __builtin_amdgcn_rcpf(1.f + eB);
        if (r < 8) {
            hswA[cur ^ 1][wsw] = hnA;
            hswB[cur ^ 1][wsw] = hnB;
        }

        if (do_stage) {
            *(float4*)(&xwlA[cb ^ 1][t][pos]) = stgA;
            *(float4*)(&xwlB[cb ^ 1][t][pos]) = stgB;
        }
        barrier_nodrain();
        cur ^= 1;
    }

    if (tid < 32) {
        const float4 hv = *(const float4*)(&hswA[cur][12 * (tid >> 1) + 4 * (tid & 1)]);
        *(float4*)(hfin + (size_t)(2 * blk) * HH + 4 * tid) = hv;
    } else if (tid < 64) {
        const int t2 = tid - 32;
        const float4 hv = *(const float4*)(&hswB[cur][12 * (t2 >> 1) + 4 * (t2 & 1)]);
        *(float4*)(hfin + (size_t)(2 * blk + 1) * HH + 4 * t2) = hv;
    }
}

// =====================================================================
__global__ __launch_bounds__(128)
void fc_k(const float* __restrict__ hlast, const float* __restrict__ fc_w,
          const float* __restrict__ fc_b, float* __restrict__ out)
{
    const int b = blockIdx.x;
    const int tid = threadIdx.x;
    __shared__ __align__(16) float h[HH];
    h[tid] = hlast[(size_t)b * HH + tid];
    __syncthreads();
    if (tid < NC) {
        float a = fc_b[tid];
        const float* wr = fc_w + tid * HH;
        #pragma unroll 4
        for (int k = 0; k < HH; ++k) a += h[k] * wr[k];
        out[(size_t)b * NC + tid] = a;
    }
}

extern "C" void kernel_launch(void* const* d_in, const int* in_sizes, int n_in,
                              void* d_out, int out_size, void* d_ws, size_t ws_size,
                              hipStream_t stream) {
    const float* x     = (const float*)d_in[0];   // (512,256,28)
    const float* w_ih0 = (const float*)d_in[1];   // (128,28)
    const float* w_hh0 = (const float*)d_in[2];   // (128,128)
    const float* b_ih0 = (const float*)d_in[3];
    const float* b_hh0 = (const float*)d_in[4];
    const float* w_ih  = (const float*)d_in[5];   // (3,128,128)
    const float* w_hh  = (const float*)d_in[6];   // (3,128,128)
    const float* b_ih  = (const float*)d_in[7];   // (3,128)
    const float* b_hh  = (const float*)d_in[8];
    const float* fc_w  = (const float*)d_in[9];   // (10,128)
    const float* fc_b  = (const float*)d_in[10];
    float* out = (float*)d_out;

    float* buf  = (float*)d_ws;                   // (B,S,H) fp32 = 64 MB
    float* hfin = buf + (size_t)BB * SS * HH;     // (B,H)

    // layer 0 input projection (bias-free; scan adds bias)
    proj_k<28><<<(BB * SS) / 64, 256, 0, stream>>>(x, w_ih0, buf);
    // layers 0..2: 2 batches per block, rec-256 + proj-256
    scan_split2<<<BB / 2, 512, 0, stream>>>(buf, w_hh0, w_ih, b_ih0, b_hh0);
    scan_split2<<<BB / 2, 512, 0, stream>>>(buf, w_hh,
                                            w_ih + (size_t)1 * HH * HH, b_ih, b_hh);
    scan_split2<<<BB / 2, 512, 0, stream>>>(buf, w_hh + (size_t)1 * HH * HH,
                                            w_ih + (size_t)2 * HH * HH,
                                            b_ih + HH, b_hh + HH);
    // layer 3 (LAST): recurrence only, writes final h (both batches)
    scan_last2<<<BB / 2, 256, 0, stream>>>(buf, hfin, w_hh + (size_t)2 * HH * HH,
                                           b_ih + 2 * HH, b_hh + 2 * HH);
    fc_k<<<BB, 128, 0, stream>>>(hfin, fc_w, fc_b, out);
}

// Round 6
// 613.430 us; speedup vs baseline: 1.1838x; 1.1838x over previous
//
#include <hip/hip_runtime.h>

#define BB 512
#define SS 256
#define HH 128
#define NC 10

typedef float v2f __attribute__((ext_vector_type(2)));

// acc + (give from lane selected by DPP ctrl)
template<int CTRL>
__device__ __forceinline__ float dppadd(float acc, float give) {
    int t = __builtin_amdgcn_update_dpp(0, __float_as_int(give), CTRL, 0xF, 0xF, true);
    return acc + __int_as_float(t);
}

// cndmask-free reduce-scatter over the 16-lane group (verified).
// Input v[8] in permuted slot order (slot i = column 8j + (i^(r&7))).
// Returns full sum for column 8j + (r&7); copies at lanes r and r^8.
__device__ __forceinline__ float red_scatter(const float v[8], int r) {
    float s0 = dppadd<0xB1>(v[0], v[1]);    // xor1
    float s2 = dppadd<0xB1>(v[2], v[3]);
    float s4 = dppadd<0xB1>(v[4], v[5]);
    float s6 = dppadd<0xB1>(v[6], v[7]);
    s0 = dppadd<0x4E>(s0, s2);              // xor2
    s4 = dppadd<0x4E>(s4, s6);
    {   // xor4 via row_ror 4 / 12
        int t1 = __builtin_amdgcn_update_dpp(0, __float_as_int(s4), 0x124, 0xF, 0xF, true);
        int t2 = __builtin_amdgcn_update_dpp(0, __float_as_int(s4), 0x12C, 0xF, 0xF, true);
        s0 += __int_as_float((r & 4) ? t2 : t1);
    }
    s0 = dppadd<0x128>(s0, s0);             // xor8 (row_ror:8)
    return s0;
}

// Barrier without the compiler's vmcnt(0) drain (LDS-visibility only).
__device__ __forceinline__ void barrier_nodrain() {
    asm volatile("s_waitcnt lgkmcnt(0)\n\ts_barrier" ::: "memory");
}

// MAC over one h-row (swizzled LDS) with the permuted weight fragment,
// then reduce-scatter. Returns full column sum at lanes r (and r^8).
__device__ __forceinline__ float mac_red(const float* __restrict__ hrow,
                                         const v2f w[8][4], int r) {
    const v2f* hb = (const v2f*)(hrow + 12 * r);
    const v2f h0 = hb[0], h1 = hb[1], h2 = hb[2], h3 = hb[3];
    float v[8];
    #pragma unroll
    for (int i = 0; i < 8; ++i) {
        v2f a = h0 * w[i][0];
        a += h1 * w[i][1];
        a += h2 * w[i][2];
        a += h3 * w[i][3];
        v[i] = a.x + a.y;
    }
    return red_scatter(v, r);
}

// =====================================================================
// proj_k: out[m][j] = sum_d A[m][d] * W[j][d]   (NO bias — scans add it)
// Layer 0 input projection only (K=28).  (Proven kernel, unchanged.)
// =====================================================================
template<int K>
__global__ __launch_bounds__(256, 1)
void proj_k(const float* __restrict__ A, const float* __restrict__ W,
            float* __restrict__ out)
{
    constexpr int AS = ((K + 31) / 32) * 32 + 4;
    constexpr int KQ = K / 4;
    constexpr int KCW = (K < 32) ? K : 32;
    constexpr int WQ = KCW / 4;
    const int tid = threadIdx.x;
    const int tx = tid & 15;
    const int ty = tid >> 4;
    const size_t m0 = (size_t)blockIdx.x * 64;

    __shared__ float Arm[64 * AS];
    __shared__ float Wst[128 * 36];

    for (int idx = tid; idx < 64 * KQ; idx += 256) {
        const int row = idx / KQ, kq = idx % KQ;
        const float4 v = *(const float4*)(A + (m0 + row) * K + 4 * kq);
        *(float4*)(&Arm[row * AS + 4 * kq]) = v;
    }

    float acc[4][8];
    #pragma unroll
    for (int c = 0; c < 8; ++c)
        #pragma unroll
        for (int r = 0; r < 4; ++r) acc[r][c] = 0.f;

    #pragma unroll 1
    for (int kc = 0; kc < K; kc += KCW) {
        __syncthreads();
        for (int idx = tid; idx < 128 * WQ; idx += 256) {
            const int col = idx / WQ, q = idx % WQ;
            const float4 v = *(const float4*)(W + (size_t)col * K + kc + 4 * q);
            *(float4*)(&Wst[col * 36 + 4 * q]) = v;
        }
        __syncthreads();
        #pragma unroll 2
        for (int q = 0; q < WQ; ++q) {
            float4 av[4];
            #pragma unroll
            for (int r = 0; r < 4; ++r)
                av[r] = *(const float4*)(&Arm[(ty + 16 * r) * AS + kc + 4 * q]);
            #pragma unroll
            for (int c = 0; c < 8; ++c) {
                const float4 wv = *(const float4*)(&Wst[(tx + 16 * c) * 36 + 4 * q]);
                #pragma unroll
                for (int r = 0; r < 4; ++r)
                    acc[r][c] += av[r].x * wv.x + av[r].y * wv.y
                               + av[r].z * wv.z + av[r].w * wv.w;
            }
        }
    }

    #pragma unroll
    for (int r = 0; r < 4; ++r)
        #pragma unroll
        for (int c = 0; c < 8; ++c)
            out[(m0 + ty + 16 * r) * HH + tx + 16 * c] = acc[r][c];
}

// =====================================================================
// scan_pair: TWO stacked RNN layers (A = L, B = L+1) wavefront-pipelined
// with skew 2, TWO batches per block. 1024 threads = 4 roles x 256:
//   role 0: rec layer A       h_A(s)=tanh(biasA+xw_A(s)+h_A(s-1)W_hhA^T), s=T
//   role 1: proj layer A      ring[(s-1)&1] = h_A(s-1) @ W_ihB^T   (+staging)
//   role 2: rec layer B       reads ring, s = T-2
//   role 3: proj layer B      buf(s-1) = h_B(s-1) @ W_ihC^T  (absent if LASTPAIR)
// Each thread holds exactly ONE weight fragment (64 floats) and handles
// 2 batches — R5's proven register footprint. Grid 256 -> 1 block/CU,
// 4 chains/CU (2 layers x 2 batches): fills the ~750cyc/step dependency
// idle that R0-R5 proved invariant at 2 chains/CU.
// Ring timing (verified in R1): value k written at T=k+1 slot k&1, read
// at T=k+2; one barrier between. In-place buf: row X last read (staging)
// at T=X-8, written by projB at T=X+3.
// =====================================================================
template<bool LASTPAIR>
__global__ __attribute__((amdgpu_flat_work_group_size(768, 1024),
                          amdgpu_waves_per_eu(4, 4)))
void scan_pair(float* __restrict__ buf, float* __restrict__ hfin,
               const float* __restrict__ w_hhA, const float* __restrict__ w_ihB,
               const float* __restrict__ w_hhB, const float* __restrict__ w_ihC,
               const float* __restrict__ bA_ih, const float* __restrict__ bA_hh,
               const float* __restrict__ bB_ih, const float* __restrict__ bB_hh)
{
    const int blk  = blockIdx.x;
    const int tid  = threadIdx.x;
    const int role = tid >> 8;       // 0 recA, 1 projA, 2 recB, 3 projB
    const int t256 = tid & 255;
    const int j   = t256 >> 4;       // col group: cols 8j..8j+7
    const int r   = t256 & 15;       // k-chunk [8r, 8r+8)
    const int g7  = r & 7;
    const int cc  = 8 * j + g7;      // column this lane finalizes
    const int wsw = 12 * j + g7;     // its swizzled LDS word

    float* const rowA = buf + (size_t)(2 * blk) * SS * HH;
    float* const rowB = rowA + (size_t)SS * HH;

    // per-role weight matrix (ONE per thread) and bias
    const float* wsrc = (role == 0) ? w_hhA
                      : (role == 1) ? w_ihB
                      : (role == 2) ? w_hhB : w_ihC;
    float bias = 0.f;
    if (role == 0) bias = bA_ih[cc] + bA_hh[cc];
    if (role == 2) bias = bB_ih[cc] + bB_hh[cc];

    v2f w[8][4];
    #pragma unroll
    for (int i = 0; i < 8; ++i) {
        const v2f* p = (const v2f*)(wsrc + (size_t)(8 * j + (i ^ g7)) * HH + 8 * r);
        w[i][0] = p[0]; w[i][1] = p[1]; w[i][2] = p[2]; w[i][3] = p[3];
    }

    __shared__ float hA_A[2][192], hA_B[2][192];   // layer A h dbuf, 2 batches
    __shared__ float hB_A[2][192], hB_B[2][192];   // layer B
    __shared__ float xwlA[2][8][HH], xwlB[2][8][HH]; // layer-A xw staging
    __shared__ float xwrA[2][HH], xwrB[2][HH];       // inter-layer ring

    if (tid < 192) {
        hA_A[0][tid] = 0.f; hA_B[0][tid] = 0.f;
        hB_A[0][tid] = 0.f; hB_B[0][tid] = 0.f;
    }
    const int st  = t256 >> 5;           // staging: step-in-chunk
    const int pos = (t256 & 31) * 4;     // staging: column (float4)
    if (role == 1) {                     // stage xw_A for steps 0..7
        const float4 vA = *(const float4*)(rowA + (size_t)st * HH + pos);
        const float4 vB = *(const float4*)(rowB + (size_t)st * HH + pos);
        *(float4*)(&xwlA[0][st][pos]) = vA;
        *(float4*)(&xwlB[0][st][pos]) = vB;
    }
    __syncthreads();

    const int TEND = SS + 3;
    for (int T = 0; T < TEND; ++T) {
        const int cur = T & 1;

        if (role == 0) {
            // ---- rec layer A, s = T ----
            if (T < SS) {
                const int ph = T & 7, cb = (T >> 3) & 1;
                const float xwA = xwlA[cb][ph][cc] + bias;
                const float xwB = xwlB[cb][ph][cc] + bias;
                const float zA = mac_red(hA_A[cur], w, r) + xwA;
                const float zB = mac_red(hA_B[cur], w, r) + xwB;
                const float eA = __expf(2.f * zA);
                const float eB = __expf(2.f * zB);
                const float nA = 1.f - 2.f * __builtin_amdgcn_rcpf(1.f + eA);
                const float nB = 1.f - 2.f * __builtin_amdgcn_rcpf(1.f + eB);
                if (r < 8) { hA_A[cur ^ 1][wsw] = nA; hA_B[cur ^ 1][wsw] = nB; }
            }
        } else if (role == 1) {
            // ---- staging + proj layer A (h_A(T-1) -> ring) ----
            if (T < SS && (T & 7) == 0 && T + 8 < SS) {
                const int cb = (T >> 3) & 1;
                const float4 vA = *(const float4*)(rowA + (size_t)(T + 8 + st) * HH + pos);
                const float4 vB = *(const float4*)(rowB + (size_t)(T + 8 + st) * HH + pos);
                *(float4*)(&xwlA[cb ^ 1][st][pos]) = vA;
                *(float4*)(&xwlB[cb ^ 1][st][pos]) = vB;
            }
            if (T >= 1 && T <= SS) {
                const float pA = mac_red(hA_A[cur], w, r);
                const float pB = mac_red(hA_B[cur], w, r);
                if (r < 8) { xwrA[cur ^ 1][cc] = pA; xwrB[cur ^ 1][cc] = pB; }
            }
        } else if (role == 2) {
            // ---- rec layer B, s = T - 2, xw from ring ----
            const int s = T - 2;
            if (s >= 0 && s < SS) {
                const float xwA = xwrA[cur][cc] + bias;
                const float xwB = xwrB[cur][cc] + bias;
                const float zA = mac_red(hB_A[cur], w, r) + xwA;
                const float zB = mac_red(hB_B[cur], w, r) + xwB;
                const float eA = __expf(2.f * zA);
                const float eB = __expf(2.f * zB);
                const float nA = 1.f - 2.f * __builtin_amdgcn_rcpf(1.f + eA);
                const float nB = 1.f - 2.f * __builtin_amdgcn_rcpf(1.f + eB);
                if (r < 8) { hB_A[cur ^ 1][wsw] = nA; hB_B[cur ^ 1][wsw] = nB; }
            }
        } else if (!LASTPAIR) {
            // ---- proj layer B (h_B(s-1) -> buf, bias-free) ----
            const int s = T - 2;
            if (s >= 1 && s <= SS) {
                const float pA = mac_red(hB_A[cur], w, r);
                const float pB = mac_red(hB_B[cur], w, r);
                if (r < 8) {
                    rowA[(size_t)(s - 1) * HH + cc] = pA;
                    rowB[(size_t)(s - 1) * HH + cc] = pB;
                }
            }
        }
        barrier_nodrain();
    }

    // LASTPAIR: h_B(255) was written at T=257 into hB_*[0]
    if (LASTPAIR && role == 0) {
        if (t256 < 32) {
            const float4 hv = *(const float4*)(&hB_A[0][12 * (t256 >> 1) + 4 * (t256 & 1)]);
            *(float4*)(hfin + (size_t)(2 * blk) * HH + 4 * t256) = hv;
        } else if (t256 < 64) {
            const int t2 = t256 - 32;
            const float4 hv = *(const float4*)(&hB_B[0][12 * (t2 >> 1) + 4 * (t2 & 1)]);
            *(float4*)(hfin + (size_t)(2 * blk + 1) * HH + 4 * t2) = hv;
        }
    }
}

// =====================================================================
__global__ __launch_bounds__(128)
void fc_k(const float* __restrict__ hlast, const float* __restrict__ fc_w,
          const float* __restrict__ fc_b, float* __restrict__ out)
{
    const int b = blockIdx.x;
    const int tid = threadIdx.x;
    __shared__ __align__(16) float h[HH];
    h[tid] = hlast[(size_t)b * HH + tid];
    __syncthreads();
    if (tid < NC) {
        float a = fc_b[tid];
        const float* wr = fc_w + tid * HH;
        #pragma unroll 4
        for (int k = 0; k < HH; ++k) a += h[k] * wr[k];
        out[(size_t)b * NC + tid] = a;
    }
}

extern "C" void kernel_launch(void* const* d_in, const int* in_sizes, int n_in,
                              void* d_out, int out_size, void* d_ws, size_t ws_size,
                              hipStream_t stream) {
    const float* x     = (const float*)d_in[0];   // (512,256,28)
    const float* w_ih0 = (const float*)d_in[1];   // (128,28)
    const float* w_hh0 = (const float*)d_in[2];   // (128,128)
    const float* b_ih0 = (const float*)d_in[3];
    const float* b_hh0 = (const float*)d_in[4];
    const float* w_ih  = (const float*)d_in[5];   // (3,128,128) feeds layers 1..3
    const float* w_hh  = (const float*)d_in[6];   // (3,128,128) layers 1..3
    const float* b_ih  = (const float*)d_in[7];   // (3,128)
    const float* b_hh  = (const float*)d_in[8];
    const float* fc_w  = (const float*)d_in[9];   // (10,128)
    const float* fc_b  = (const float*)d_in[10];
    float* out = (float*)d_out;

    float* buf  = (float*)d_ws;                   // (B,S,H) fp32 = 64 MB
    float* hfin = buf + (size_t)BB * SS * HH;     // (B,H)

    // layer 0 input projection (bias-free; scans add bias)
    proj_k<28><<<(BB * SS) / 64, 256, 0, stream>>>(x, w_ih0, buf);
    // layers 0+1 fused (projB writes layer-2 xw into buf)
    scan_pair<false><<<BB / 2, 1024, 0, stream>>>(
        buf, hfin,
        w_hh0,                         // recA: layer 0
        w_ih,                          // projA: feeds layer 1
        w_hh,                          // recB: layer 1
        w_ih + (size_t)1 * HH * HH,    // projB: feeds layer 2
        b_ih0, b_hh0, b_ih, b_hh);
    // layers 2+3 fused (no projB; writes final h)
    scan_pair<true><<<BB / 2, 768, 0, stream>>>(
        buf, hfin,
        w_hh + (size_t)1 * HH * HH,    // recA: layer 2
        w_ih + (size_t)2 * HH * HH,    // projA: feeds layer 3
        w_hh + (size_t)2 * HH * HH,    // recB: layer 3
        nullptr,
        b_ih + HH, b_hh + HH, b_ih + 2 * HH, b_hh + 2 * HH);
    fc_k<<<BB, 128, 0, stream>>>(hfin, fc_w, fc_b, out);
}

// Round 7
// 541.441 us; speedup vs baseline: 1.3412x; 1.1330x over previous
//
#include <hip/hip_runtime.h>

#define BB 512
#define SS 256
#define HH 128
#define NC 10

typedef float v2f __attribute__((ext_vector_type(2)));

// acc + (give from lane selected by DPP ctrl)
template<int CTRL>
__device__ __forceinline__ float dppadd(float acc, float give) {
    int t = __builtin_amdgcn_update_dpp(0, __float_as_int(give), CTRL, 0xF, 0xF, true);
    return acc + __int_as_float(t);
}

// cndmask-free reduce-scatter over the 16-lane group (verified).
// Input v[8] in permuted slot order (slot i = column 8j + (i^(r&7))).
// Returns full sum for column 8j + (r&7); copies at lanes r and r^8.
__device__ __forceinline__ float red_scatter(const float v[8], int r) {
    float s0 = dppadd<0xB1>(v[0], v[1]);    // xor1
    float s2 = dppadd<0xB1>(v[2], v[3]);
    float s4 = dppadd<0xB1>(v[4], v[5]);
    float s6 = dppadd<0xB1>(v[6], v[7]);
    s0 = dppadd<0x4E>(s0, s2);              // xor2
    s4 = dppadd<0x4E>(s4, s6);
    {   // xor4 via row_ror 4 / 12
        int t1 = __builtin_amdgcn_update_dpp(0, __float_as_int(s4), 0x124, 0xF, 0xF, true);
        int t2 = __builtin_amdgcn_update_dpp(0, __float_as_int(s4), 0x12C, 0xF, 0xF, true);
        s0 += __int_as_float((r & 4) ? t2 : t1);
    }
    s0 = dppadd<0x128>(s0, s0);             // xor8 (row_ror:8)
    return s0;
}

// Barrier without the compiler's vmcnt(0) drain (LDS-visibility only).
__device__ __forceinline__ void barrier_nodrain() {
    asm volatile("s_waitcnt lgkmcnt(0)\n\ts_barrier" ::: "memory");
}

// K=128 MAC (4 v2f weights) + reduce-scatter.
__device__ __forceinline__ float mac4_red(const float* __restrict__ hb_,
                                          const v2f w[8][8], int r) {
    const v2f* hb = (const v2f*)hb_;
    const v2f h0 = hb[0], h1 = hb[1], h2 = hb[2], h3 = hb[3];
    float v[8];
    #pragma unroll
    for (int i = 0; i < 8; ++i) {
        v2f a = h0 * w[i][0];
        a += h1 * w[i][1];
        a += h2 * w[i][2];
        a += h3 * w[i][3];
        v[i] = a.x + a.y;
    }
    return red_scatter(v, r);
}

// K=256 concatenated MAC: x-half (W_ih part) + y-half (W_hh part).
__device__ __forceinline__ float mac8_red(const float* __restrict__ xb_,
                                          const float* __restrict__ yb_,
                                          const v2f w[8][8], int r) {
    const v2f* xb = (const v2f*)xb_;
    const v2f* yb = (const v2f*)yb_;
    const v2f x0 = xb[0], x1 = xb[1], x2 = xb[2], x3 = xb[3];
    const v2f y0 = yb[0], y1 = yb[1], y2 = yb[2], y3 = yb[3];
    float v[8];
    #pragma unroll
    for (int i = 0; i < 8; ++i) {
        v2f a = x0 * w[i][0];
        a += x1 * w[i][1];
        a += x2 * w[i][2];
        a += x3 * w[i][3];
        a += y0 * w[i][4];
        a += y1 * w[i][5];
        a += y2 * w[i][6];
        a += y3 * w[i][7];
        v[i] = a.x + a.y;
    }
    return red_scatter(v, r);
}

__device__ __forceinline__ float tanh_fast(float z) {
    const float e = __expf(2.f * z);
    return 1.f - 2.f * __builtin_amdgcn_rcpf(1.f + e);
}

// =====================================================================
// proj_k: out[m][j] = sum_d A[m][d] * W[j][d]   (NO bias — scans add it)
// Layer 0 input projection only (K=28).  (Proven kernel, unchanged.)
// =====================================================================
template<int K>
__global__ __launch_bounds__(256, 1)
void proj_k(const float* __restrict__ A, const float* __restrict__ W,
            float* __restrict__ out)
{
    constexpr int AS = ((K + 31) / 32) * 32 + 4;
    constexpr int KQ = K / 4;
    constexpr int KCW = (K < 32) ? K : 32;
    constexpr int WQ = KCW / 4;
    const int tid = threadIdx.x;
    const int tx = tid & 15;
    const int ty = tid >> 4;
    const size_t m0 = (size_t)blockIdx.x * 64;

    __shared__ float Arm[64 * AS];
    __shared__ float Wst[128 * 36];

    for (int idx = tid; idx < 64 * KQ; idx += 256) {
        const int row = idx / KQ, kq = idx % KQ;
        const float4 v = *(const float4*)(A + (m0 + row) * K + 4 * kq);
        *(float4*)(&Arm[row * AS + 4 * kq]) = v;
    }

    float acc[4][8];
    #pragma unroll
    for (int c = 0; c < 8; ++c)
        #pragma unroll
        for (int r = 0; r < 4; ++r) acc[r][c] = 0.f;

    #pragma unroll 1
    for (int kc = 0; kc < K; kc += KCW) {
        __syncthreads();
        for (int idx = tid; idx < 128 * WQ; idx += 256) {
            const int col = idx / WQ, q = idx % WQ;
            const float4 v = *(const float4*)(W + (size_t)col * K + kc + 4 * q);
            *(float4*)(&Wst[col * 36 + 4 * q]) = v;
        }
        __syncthreads();
        #pragma unroll 2
        for (int q = 0; q < WQ; ++q) {
            float4 av[4];
            #pragma unroll
            for (int r = 0; r < 4; ++r)
                av[r] = *(const float4*)(&Arm[(ty + 16 * r) * AS + kc + 4 * q]);
            #pragma unroll
            for (int c = 0; c < 8; ++c) {
                const float4 wv = *(const float4*)(&Wst[(tx + 16 * c) * 36 + 4 * q]);
                #pragma unroll
                for (int r = 0; r < 4; ++r)
                    acc[r][c] += av[r].x * wv.x + av[r].y * wv.y
                               + av[r].z * wv.z + av[r].w * wv.w;
            }
        }
    }

    #pragma unroll
    for (int r = 0; r < 4; ++r)
        #pragma unroll
        for (int c = 0; c < 8; ++c)
            out[(m0 + ty + 16 * r) * HH + tx + 16 * c] = acc[r][c];
}

// =====================================================================
// scan_fuse<PAIR>: TWO stacked layers via combined-K recurrence, 2
// batches per block, 512 threads = role0 (layer 2*PAIR) + role1 (layer
// 2*PAIR+1). The projection GEMV is FUSED into the next layer's
// recurrence as one K=256 MAC: h_B(s) = tanh(b + [h_A(s) ‖ h_B(s-1)]
// @ [W_ih ‖ W_hh]^T) — eliminates the separate proj reduce, tail, and
// xw ring (R6 counters: issue-bound, 116 instr/chain-step; this is
// ~75). 512-thr block + waves_per_eu(2,2) = 256-reg cap: the 128
// weight floats of the K=256 role fit (R0/R5 precedent; R1's spill was
// this footprint at cap 128 — avoided).
//   PAIR=0: role0 = layer0 (staged xw0 + K=128 W_hh0);
//           role1 = layer1 (K=256), writes h1 rows to buf (plain).
//   PAIR=1: role0 = layer2 (K=256, x-half = STAGED h1 rows);
//           role1 = layer3 (K=256), final h -> hfin.
// Staging buffer uses the same 12-word swizzle as hsw (float4 writes
// stay contiguous: offset within each 8-group is 0 or 4), so K=256 row
// reads are 2-way-bank-free like hsw.
// Skew: role1 at T computes h_B(T-1); both roles read dbuf[cur=T&1],
// write [cur^1]. In-place: row X staged at T=X-8, h1-written at T=X+1.
// =====================================================================
template<int PAIR>
__global__ __attribute__((amdgpu_flat_work_group_size(512, 512),
                          amdgpu_waves_per_eu(2, 2)))
void scan_fuse(float* __restrict__ buf, float* __restrict__ hfin,
               const float* __restrict__ w_r0_a, const float* __restrict__ w_r0_b,
               const float* __restrict__ w_r1_a, const float* __restrict__ w_r1_b,
               const float* __restrict__ b0_ih, const float* __restrict__ b0_hh,
               const float* __restrict__ b1_ih, const float* __restrict__ b1_hh)
{
    const int blk  = blockIdx.x;
    const int tid  = threadIdx.x;
    const int role = tid >> 8;       // 0 = layer A, 1 = layer B (combined-K)
    const int t256 = tid & 255;
    const int j   = t256 >> 4;       // col group: cols 8j..8j+7
    const int r   = t256 & 15;       // k-chunk [8r, 8r+8)
    const int g7  = r & 7;
    const int cc  = 8 * j + g7;      // column this lane finalizes
    const int wsw = 12 * j + g7;     // swizzled word for cc

    float* const rowA = buf + (size_t)(2 * blk) * SS * HH;
    float* const rowB = rowA + (size_t)SS * HH;
    const float bias = role ? (b1_ih[cc] + b1_hh[cc]) : (b0_ih[cc] + b0_hh[cc]);

    // permuted weights: slot i = column 8j + (i^g7); [0..3] = x-half
    // (W_ih or W_hh0), [4..7] = y-half (W_hh) for combined-K roles.
    const float* wa = role ? w_r1_a : w_r0_a;
    const float* wb = role ? w_r1_b : w_r0_b;
    v2f w[8][8];
    #pragma unroll
    for (int i = 0; i < 8; ++i) {
        const size_t col = (size_t)(8 * j + (i ^ g7));
        const v2f* pa = (const v2f*)(wa + col * HH + 8 * r);
        w[i][0] = pa[0]; w[i][1] = pa[1]; w[i][2] = pa[2]; w[i][3] = pa[3];
        if (PAIR == 1 || role == 1) {
            const v2f* pb = (const v2f*)(wb + col * HH + 8 * r);
            w[i][4] = pb[0]; w[i][5] = pb[1]; w[i][6] = pb[2]; w[i][7] = pb[3];
        }
    }

    __shared__ float hsw[2][2][2][192];   // [layer][batch][dbuf][192], swizzled
    __shared__ float stg[2][8][2][192];   // [chunk][step][batch][192], swizzled

    for (int i = tid; i < 2 * 2 * 2 * 192; i += 512) ((float*)hsw)[i] = 0.f;

    const int st  = t256 >> 5;            // staging: step-in-chunk
    const int m32 = t256 & 31;            // staging: float4 index in row
    const int spw = 12 * (m32 >> 1) + 4 * (m32 & 1);  // swizzled float4 word
    if (role == 0) {                      // stage rows 0..7 (xw0 or h1)
        const float4 vA = *(const float4*)(rowA + (size_t)st * HH + 4 * m32);
        const float4 vB = *(const float4*)(rowB + (size_t)st * HH + 4 * m32);
        *(float4*)(&stg[0][st][0][spw]) = vA;
        *(float4*)(&stg[0][st][1][spw]) = vB;
    }
    __syncthreads();

    for (int T = 0; T <= SS; ++T) {
        const int cur = T & 1;

        if (role == 0) {
            if (T < SS) {
                const int ph = T & 7, cb = (T >> 3) & 1;
                if ((T & 7) == 0 && T + 8 < SS) {
                    const float4 vA = *(const float4*)(rowA + (size_t)(T + 8 + st) * HH + 4 * m32);
                    const float4 vB = *(const float4*)(rowB + (size_t)(T + 8 + st) * HH + 4 * m32);
                    *(float4*)(&stg[cb ^ 1][st][0][spw]) = vA;
                    *(float4*)(&stg[cb ^ 1][st][1][spw]) = vB;
                }
                float zA, zB;
                if (PAIR == 0) {
                    zA = stg[cb][ph][0][wsw] + bias
                       + mac4_red(&hsw[0][0][cur][12 * r], w, r);
                    zB = stg[cb][ph][1][wsw] + bias
                       + mac4_red(&hsw[0][1][cur][12 * r], w, r);
                } else {
                    zA = bias + mac8_red(&stg[cb][ph][0][12 * r],
                                         &hsw[0][0][cur][12 * r], w, r);
                    zB = bias + mac8_red(&stg[cb][ph][1][12 * r],
                                         &hsw[0][1][cur][12 * r], w, r);
                }
                const float nA = tanh_fast(zA);
                const float nB = tanh_fast(zB);
                if (r < 8) {
                    hsw[0][0][cur ^ 1][wsw] = nA;
                    hsw[0][1][cur ^ 1][wsw] = nB;
                }
            }
        } else {
            if (T >= 1) {
                const float zA = bias + mac8_red(&hsw[0][0][cur][12 * r],
                                                 &hsw[1][0][cur][12 * r], w, r);
                const float zB = bias + mac8_red(&hsw[0][1][cur][12 * r],
                                                 &hsw[1][1][cur][12 * r], w, r);
                const float nA = tanh_fast(zA);
                const float nB = tanh_fast(zB);
                if (r < 8) {
                    hsw[1][0][cur ^ 1][wsw] = nA;
                    hsw[1][1][cur ^ 1][wsw] = nB;
                    if (PAIR == 0) {   // persist h1 for dispatch 2
                        rowA[(size_t)(T - 1) * HH + cc] = nA;
                        rowB[(size_t)(T - 1) * HH + cc] = nB;
                    }
                }
            }
        }
        barrier_nodrain();
    }

    // PAIR=1: h3(SS-1) written at T=SS into dbuf[1]
    if (PAIR == 1 && role == 1) {
        if (t256 < 32) {
            const float4 hv = *(const float4*)(&hsw[1][0][1][12 * (t256 >> 1) + 4 * (t256 & 1)]);
            *(float4*)(hfin + (size_t)(2 * blk) * HH + 4 * t256) = hv;
        } else if (t256 < 64) {
            const int t2 = t256 - 32;
            const float4 hv = *(const float4*)(&hsw[1][1][1][12 * (t2 >> 1) + 4 * (t2 & 1)]);
            *(float4*)(hfin + (size_t)(2 * blk + 1) * HH + 4 * t2) = hv;
        }
    }
}

// =====================================================================
__global__ __launch_bounds__(128)
void fc_k(const float* __restrict__ hlast, const float* __restrict__ fc_w,
          const float* __restrict__ fc_b, float* __restrict__ out)
{
    const int b = blockIdx.x;
    const int tid = threadIdx.x;
    __shared__ __align__(16) float h[HH];
    h[tid] = hlast[(size_t)b * HH + tid];
    __syncthreads();
    if (tid < NC) {
        float a = fc_b[tid];
        const float* wr = fc_w + tid * HH;
        #pragma unroll 4
        for (int k = 0; k < HH; ++k) a += h[k] * wr[k];
        out[(size_t)b * NC + tid] = a;
    }
}

extern "C" void kernel_launch(void* const* d_in, const int* in_sizes, int n_in,
                              void* d_out, int out_size, void* d_ws, size_t ws_size,
                              hipStream_t stream) {
    const float* x     = (const float*)d_in[0];   // (512,256,28)
    const float* w_ih0 = (const float*)d_in[1];   // (128,28)
    const float* w_hh0 = (const float*)d_in[2];   // (128,128)
    const float* b_ih0 = (const float*)d_in[3];
    const float* b_hh0 = (const float*)d_in[4];
    const float* w_ih  = (const float*)d_in[5];   // (3,128,128): layers 1..3 input proj
    const float* w_hh  = (const float*)d_in[6];   // (3,128,128): layers 1..3 recurrent
    const float* b_ih  = (const float*)d_in[7];   // (3,128)
    const float* b_hh  = (const float*)d_in[8];
    const float* fc_w  = (const float*)d_in[9];   // (10,128)
    const float* fc_b  = (const float*)d_in[10];
    float* out = (float*)d_out;

    float* buf  = (float*)d_ws;                   // (B,S,H) fp32 = 64 MB
    float* hfin = buf + (size_t)BB * SS * HH;     // (B,H)

    // layer 0 input projection (bias-free; scans add bias)
    proj_k<28><<<(BB * SS) / 64, 256, 0, stream>>>(x, w_ih0, buf);
    // layers 0+1: role0 = layer0 rec (staged xw0), role1 = layer1
    // combined-K (writes h1 rows into buf)
    scan_fuse<0><<<BB / 2, 512, 0, stream>>>(
        buf, hfin,
        w_hh0, nullptr,
        w_ih, w_hh,                                  // layer 1: W_ih1, W_hh1
        b_ih0, b_hh0, b_ih, b_hh);
    // layers 2+3: role0 = layer2 combined-K (x-half = staged h1 rows),
    // role1 = layer3 combined-K (writes final h)
    scan_fuse<1><<<BB / 2, 512, 0, stream>>>(
        buf, hfin,
        w_ih + (size_t)1 * HH * HH, w_hh + (size_t)1 * HH * HH,  // layer 2
        w_ih + (size_t)2 * HH * HH, w_hh + (size_t)2 * HH * HH,  // layer 3
        b_ih + HH, b_hh + HH, b_ih + 2 * HH, b_hh + 2 * HH);
    fc_k<<<BB, 128, 0, stream>>>(hfin, fc_w, fc_b, out);
}